// Round 8
// baseline (35.397 us; speedup 1.0000x reference)
//
#include <hip/hip_runtime.h>
#include <hip/hip_bf16.h>

// RoI pooling (ROI-Align bilinear, A=7) on NHWC fp32 feature map.
// features_map: (1, 128, 128, 256) fp32
// boxes:        (2000, 4) int32  [x1, y1, x2, y2]
// out:          (2000, 1, 7, 7, 256) fp32
//
// Round-8: 4 samples per wave for memory-level parallelism.
//  - Kernel 1 (1 block): counting-sort box indices by spatial bucket
//    ((y1>>4)<<3 | (x1>>4)) into order[] (d_ws). Output goes to the
//    ORIGINAL box position, so output bytes are sort-invariant.
//  - Kernel 2: one wave per 4 consecutive sorted samples -> 16 independent
//    1KB gather loads in flight per wave (vs 4), 4 NT stores; 24.5K waves.
//    Chunked bijective XCD swizzle keeps each XCD on a spatially-contiguous
//    box range so gathers hit per-XCD L2 (round-7: 52->34us from this).
//  - nontemporal stores for the 100 MB streaming output.

#define FM_H 128
#define FM_W 128
#define FM_C 256
#define ANCH 7
#define NSAMP (ANCH * ANCH)
#define SPW 4   // samples per wave

typedef float f4 __attribute__((ext_vector_type(4)));

__global__ __launch_bounds__(256) void sort_boxes_kernel(
    const int* __restrict__ boxes, int* __restrict__ order, int n_boxes)
{
    __shared__ int cursor[64];
    const int tid = threadIdx.x;
    if (tid < 64) cursor[tid] = 0;
    __syncthreads();

    for (int i = tid; i < n_boxes; i += 256) {
        const int x1 = boxes[i * 4 + 0];
        const int y1 = boxes[i * 4 + 1];
        const int key = ((y1 >> 4) << 3) | (x1 >> 4);
        atomicAdd(&cursor[key], 1);
    }
    __syncthreads();

    if (tid == 0) {
        int run = 0;
        for (int k = 0; k < 64; ++k) {
            int c = cursor[k];
            cursor[k] = run;
            run += c;
        }
    }
    __syncthreads();

    for (int i = tid; i < n_boxes; i += 256) {
        const int x1 = boxes[i * 4 + 0];
        const int y1 = boxes[i * 4 + 1];
        const int key = ((y1 >> 4) << 3) | (x1 >> 4);
        const int pos = atomicAdd(&cursor[key], 1);
        order[pos] = i;
    }
}

__global__ __launch_bounds__(256) void roi_pool_kernel(
    const float* __restrict__ fm,
    const int* __restrict__ boxes,
    const int* __restrict__ order,
    float* __restrict__ out,
    int n_samples)  // N * 49
{
    // chunked bijective XCD swizzle
    const int nb  = gridDim.x;
    const int b   = blockIdx.x;
    const int q   = nb >> 3;
    const int r   = nb & 7;
    const int xcd = b & 7;
    const int idx = b >> 3;
    const int sb  = (xcd < r ? xcd * (q + 1) : r * (q + 1) + (xcd - r) * q) + idx;

    const int lane = threadIdx.x & 63;
    // first sorted-sample id of this wave's group of SPW, wave-uniform
    const int g0 = __builtin_amdgcn_readfirstlane(
        ((sb << 2) + (threadIdx.x >> 6)) * SPW);

    // ---- phase 1: issue all 4*SPW gather loads (independent, in flight) ----
    f4 v00[SPW], v01[SPW], v10[SPW], v11[SPW];
    float fxs[SPW], fys[SPW];
    size_t dsts[SPW];
    #pragma unroll
    for (int j = 0; j < SPW; ++j) {
        const int g = g0 + j;
        const bool live = (g < n_samples);
        const int gg = live ? g : 0;

        const int sorted_box = gg / NSAMP;
        const int s   = gg - sorted_box * NSAMP;
        const int py  = s / ANCH;
        const int px  = s - py * ANCH;
        const int box = order[sorted_box];

        const int x1 = boxes[box * 4 + 0];
        const int y1 = boxes[box * 4 + 1];
        const int x2 = boxes[box * 4 + 2];
        const int y2 = boxes[box * 4 + 3];

        const float spany = (float)(y2 - y1);
        float sy = ((float)py + 0.5f) * (spany / (float)ANCH) - 0.5f;
        sy = fminf(fmaxf(sy, 0.0f), fmaxf(spany - 1.0f, 0.0f));
        const int iy0 = (int)floorf(sy);
        const int iy1 = min(iy0 + 1, y2 - y1 - 1);
        fys[j] = sy - (float)iy0;
        const int ys0 = iy0 + y1;
        const int ys1 = iy1 + y1;

        const float spanx = (float)(x2 - x1);
        float sx = ((float)px + 0.5f) * (spanx / (float)ANCH) - 0.5f;
        sx = fminf(fmaxf(sx, 0.0f), fmaxf(spanx - 1.0f, 0.0f));
        const int ix0 = (int)floorf(sx);
        const int ix1 = min(ix0 + 1, x2 - x1 - 1);
        fxs[j] = sx - (float)ix0;
        const int xs0 = ix0 + x1;
        const int xs1 = ix1 + x1;

        const f4* p00 = (const f4*)(fm + ((size_t)ys0 * FM_W + xs0) * FM_C);
        const f4* p01 = (const f4*)(fm + ((size_t)ys0 * FM_W + xs1) * FM_C);
        const f4* p10 = (const f4*)(fm + ((size_t)ys1 * FM_W + xs0) * FM_C);
        const f4* p11 = (const f4*)(fm + ((size_t)ys1 * FM_W + xs1) * FM_C);

        v00[j] = p00[lane];
        v01[j] = p01[lane];
        v10[j] = p10[lane];
        v11[j] = p11[lane];

        dsts[j] = live ? ((size_t)box * NSAMP + s) * FM_C : (size_t)0;
    }

    // ---- phase 2: lerp + NT store per sample ----
    #pragma unroll
    for (int j = 0; j < SPW; ++j) {
        if (g0 + j >= n_samples) break;
        const float fx = fxs[j], fy = fys[j];
        const float gx = 1.0f - fx, gy = 1.0f - fy;
        f4 res;
        #pragma unroll
        for (int c = 0; c < 4; ++c) {
            float top = v00[j][c] * gx + v01[j][c] * fx;
            float bot = v10[j][c] * gx + v11[j][c] * fx;
            res[c] = top * gy + bot * fy;
        }
        f4* dst = (f4*)(out + dsts[j]);
        __builtin_nontemporal_store(res, &dst[lane]);
    }
}

extern "C" void kernel_launch(void* const* d_in, const int* in_sizes, int n_in,
                              void* d_out, int out_size, void* d_ws, size_t ws_size,
                              hipStream_t stream) {
    const float* fm    = (const float*)d_in[0];   // (1,128,128,256) fp32
    const int*   boxes = (const int*)d_in[1];     // (N,4) int32
    // d_in[2] = anchor_size scalar (7); layout constants hard-coded to setup.

    const int N = in_sizes[1] / 4;
    const int n_samples = N * NSAMP;

    float* out  = (float*)d_out;
    int* order  = (int*)d_ws;                      // N ints of scratch

    sort_boxes_kernel<<<1, 256, 0, stream>>>(boxes, order, N);

    const int threads = 256;                       // 4 waves/block
    const int samples_per_block = (threads / 64) * SPW;   // 16
    const int grid = (n_samples + samples_per_block - 1) / samples_per_block;

    roi_pool_kernel<<<grid, threads, 0, stream>>>(fm, boxes, order, out, n_samples);
}